// Round 12
// baseline (112.694 us; speedup 1.0000x reference)
//
#include <hip/hip_runtime.h>
#include <hip/hip_bf16.h>

typedef __bf16 bf16x8 __attribute__((ext_vector_type(8)));
typedef float f32x4 __attribute__((ext_vector_type(4)));

#define LOG2E 1.4426950408889634f
#define LAMBDA_INIT 0.3555090675909693f
#define CEXP 0.18033688011112042f   // 0.125 * LOG2E
#define MOFF 11.541560327111708f    // 8 * LOG2E  (fixed raw max = 64)

// ws layout (bytes):
//  q    : [0, 4.19M)       bf16 [16384][128] row-major
//  kimg : [4.19M, 8.39M)   bf16 [4][64][2][8 regions][64 slots][8]  (frag image)
//  vimg : [8.39M, 12.58M)  bf16 [4][64][16 regions][64 slots][8]    (frag image)
//  part : [12.58M, 46.66M) 2048 recs x 16640B (l[64] f32 + O[64][128] bf16)
//  WT   : [46.66M, 47.45M) bf16 [3][128][1024]
#define K_OFF   ((size_t)16384 * 128)
#define VT_OFF  ((size_t)2 * 16384 * 128)
#define PART_OFF_BYTES ((size_t)12582912)
#define WT_OFF_BYTES   ((size_t)46661632)
#define REC_FLOATS 4160  // 64 l + 4096 words of bf16 O

__device__ __forceinline__ unsigned short f2bf(float f) {
    __hip_bfloat16 h = __float2bfloat16(f);
    unsigned short u;
    __builtin_memcpy(&u, &h, 2);
    return u;
}
__device__ __forceinline__ float bf2f(unsigned short u) {
    unsigned int x = ((unsigned int)u) << 16;
    float f;
    __builtin_memcpy(&f, &x, 4);
    return f;
}
__device__ __forceinline__ unsigned int cvt_pk_bf16(float a, float b) {
    unsigned int r;
    asm volatile("v_cvt_pk_bf16_f32 %0, %1, %2" : "=v"(r) : "v"(a), "v"(b));
    return r;
}

// ---------------- W pre-transpose: [1024][128] f32 -> [128][1024] bf16 ----------------
__global__ __launch_bounds__(256) void prep_wt(
    const float* __restrict__ Wq, const float* __restrict__ Wk,
    const float* __restrict__ Wv, unsigned short* __restrict__ WT) {
    const int kt = blockIdx.x, nt = blockIdx.y, mat = blockIdx.z;
    const float* W = (mat == 0) ? Wq : (mat == 1) ? Wk : Wv;
    unsigned short* O = WT + (size_t)mat * 128 * 1024;
    __shared__ float tb[64][65];
    const int r = threadIdx.x >> 2, c4 = (threadIdx.x & 3) * 16;
    for (int j = 0; j < 4; ++j) {
        float4 v = *(const float4*)&W[(size_t)(kt * 64 + r) * 128 + nt * 64 + c4 + j * 4];
        tb[r][c4 + j * 4 + 0] = v.x;
        tb[r][c4 + j * 4 + 1] = v.y;
        tb[r][c4 + j * 4 + 2] = v.z;
        tb[r][c4 + j * 4 + 3] = v.w;
    }
    __syncthreads();
    unsigned short tmp[16];
    for (int j = 0; j < 16; ++j) tmp[j] = f2bf(tb[c4 + j][r]);
    *(uint4*)&O[(size_t)(nt * 64 + r) * 1024 + kt * 64 + c4] = *(uint4*)&tmp[0];
    *(uint4*)&O[(size_t)(nt * 64 + r) * 1024 + kt * 64 + c4 + 8] = *(uint4*)&tmp[8];
}

// ---------------- QKV projection ----------------
// grid (128, 3): the 3 mats' row-r blocks map to the SAME XCD (128 % 8 == 0).
// K and V epilogues write the attention kernel's exact LDS/reg frag image.
__global__ __launch_bounds__(256) void qkv_gemm(
    const float* __restrict__ x, const unsigned short* __restrict__ WT,
    unsigned short* __restrict__ qkv) {
    const int tid = threadIdx.x;
    const int l = tid & 63, wid = tid >> 6;
    const int g = l >> 4, i16 = l & 15;
    const int row0 = blockIdx.x * 128;
    const int mat = blockIdx.y;
    const unsigned short* Wt = WT + (size_t)mat * 128 * 1024;

    __shared__ unsigned short smem[2][128][72];
    auto xs = smem[0];
    auto wt = smem[1];

    f32x4 acc[2][8];
    const f32x4 z4 = {0.f, 0.f, 0.f, 0.f};
    for (int a = 0; a < 2; ++a)
        for (int b = 0; b < 8; ++b) acc[a][b] = z4;

    for (int k0 = 0; k0 < 1024; k0 += 64) {
        __syncthreads();
        {   // stage x tile (128 x 64) f32 -> bf16
            const int c = (tid & 15) * 4;
            const int rbase = tid >> 4;
            #pragma unroll
            for (int it = 0; it < 8; ++it) {
                int r = rbase + it * 16;
                const float4 v = *(const float4*)&x[(size_t)(row0 + r) * 1024 + k0 + c];
                ushort4 pk = make_ushort4(f2bf(v.x), f2bf(v.y), f2bf(v.z), f2bf(v.w));
                *(ushort4*)&xs[r][c] = pk;
            }
        }
        {   // stage W^T tile (128 n x 64 k) bf16 vectorized
            #pragma unroll
            for (int it = 0; it < 4; ++it) {
                int lin = it * 256 + tid;
                int n = lin >> 3, k8 = (lin & 7) * 8;
                *(uint4*)&wt[n][k8] = *(const uint4*)&Wt[(size_t)n * 1024 + k0 + k8];
            }
        }
        __syncthreads();

        bf16x8 af[2][2];
        for (int rb = 0; rb < 2; ++rb)
            for (int c = 0; c < 2; ++c)
                af[rb][c] = *(const bf16x8*)&xs[wid * 32 + rb * 16 + i16][c * 32 + 8 * g];
        for (int nb = 0; nb < 8; ++nb) {
            bf16x8 b0 = *(const bf16x8*)&wt[nb * 16 + i16][8 * g];
            bf16x8 b1 = *(const bf16x8*)&wt[nb * 16 + i16][32 + 8 * g];
            for (int rb = 0; rb < 2; ++rb) {
                acc[rb][nb] = __builtin_amdgcn_mfma_f32_16x16x32_bf16(af[rb][0], b0, acc[rb][nb], 0, 0, 0);
                acc[rb][nb] = __builtin_amdgcn_mfma_f32_16x16x32_bf16(af[rb][1], b1, acc[rb][nb], 0, 0, 0);
            }
        }
    }

    __syncthreads();
    unsigned short(*ts)[136] = (unsigned short(*)[136]) & smem[0][0][0];
    for (int rb = 0; rb < 2; ++rb)
        for (int nb = 0; nb < 8; ++nb)
            for (int r = 0; r < 4; ++r)
                ts[wid * 32 + rb * 16 + g * 4 + r][nb * 16 + i16] = f2bf(acc[rb][nb][r]);
    __syncthreads();

    const int bq = row0 >> 12;            // batch
    const int s0b = (row0 & 4095) >> 6;   // first kv-tile of this row block
    if (mat == 0) {
        unsigned short* outp = qkv + (size_t)row0 * 128;
        #pragma unroll
        for (int it = 0; it < 8; ++it) {
            int tr = it * 16 + (tid >> 4), dv0 = (tid & 15) * 8;
            *(uint4*)&outp[tr * 128 + dv0] = *(const uint4*)&ts[tr][dv0];
        }
    } else if (mat == 1) {
        // K frag image: [(b*64+s)*2+branch][region=cb*2+cc][slot=gq*16+i16][8]
        unsigned short* kimg = qkv + K_OFF;
        #pragma unroll
        for (int it = 0; it < 8; ++it) {
            int lin = it * 256 + tid;      // 0..2047 slots of the 2-tile image
            int tile = lin >> 10;
            int branch_ = (lin >> 9) & 1;
            int region = (lin >> 6) & 7;
            int slot = lin & 63;
            int row = tile * 64 + (region >> 1) * 16 + (slot & 15);
            int d = branch_ * 64 + (region & 1) * 32 + (slot >> 4) * 8;
            uint4 vv = *(const uint4*)&ts[row][d];
            size_t off = ((size_t)((bq * 64 + s0b + tile) * 2 + branch_) * 4096) + (region * 64 + slot) * 8;
            *(uint4*)&kimg[off] = vv;
        }
    } else {
        // V frag image: [b*64+s][region=nb*2+cc][slot=gq*16+i16][8], elem = kv&7
        unsigned short* vimg = qkv + VT_OFF;
        #pragma unroll
        for (int it = 0; it < 8; ++it) {
            int lin = it * 256 + tid;      // 0..2047 slots of the 2-tile image
            int tile = lin >> 10;
            int rem = lin & 1023;
            int region = rem >> 6;         // 0..15
            int slot = rem & 63;
            int dv = (region >> 1) * 16 + (slot & 15);
            int kv0 = (region & 1) * 32 + (slot >> 4) * 8;
            unsigned short tmp[8];
            #pragma unroll
            for (int e = 0; e < 8; ++e) tmp[e] = ts[tile * 64 + kv0 + e][dv];
            size_t off = ((size_t)(bq * 64 + s0b + tile) * 8192) + (region * 64 + slot) * 8;
            *(uint4*)&vimg[off] = *(uint4*)tmp;
        }
    }
}

// ---------------- Differential causal flash attention, paired rows ----------------
// grid (32, 4, 8): z = c*2+branch. Block owns adjacent row PAIR
// (t_e = 62-2bx, t_o = 63-2bx) so every staged kv-tile serves two 64-row
// q-tiles (qset A = t_e active for all s != t_o). bx=0 is the longest pair
// (LPT dispatch order). Chunks c over [0, t_o+1).
// Wave w: q-rows [w*16, w*16+16) of BOTH rows for QK/softmax; for PV the
// wave computes ALL q x dv-slice [32w, 32w+32) with V held in REGISTERS
// (direct frag-image global loads, no V LDS at all). P via 16KB psf
// (cross-wave -> barrier before PV). LDS = 24KB; 3 blocks/CU.
__global__ __launch_bounds__(256, 3) void diff_attn_pair(
    const unsigned short* __restrict__ q, const unsigned short* __restrict__ kimg,
    const unsigned short* __restrict__ vimg,
    float* __restrict__ part) {
    const int bx = blockIdx.x, b = blockIdx.y;
    const int c = blockIdx.z >> 1, branch = blockIdx.z & 1;
    const int t_o = 63 - 2 * bx, t_e = t_o - 1;
    const int n = t_o + 1;
    const int s_lo = (c * n) >> 2, smax = ((c + 1) * n) >> 2;

    const int tid = threadIdx.x;
    const int l = tid & 63, w = tid >> 6;
    const int gq = l >> 4, i16 = l & 15;
    const float NEGINF = -__builtin_inff();

    __shared__ unsigned short ksf[4096];  //  8 KB: [8 region][64 slot][8]
    __shared__ unsigned short psf[8192];  // 16 KB: [2 qset][4 qg][2 cc][64 slot][8]

    float* recA = part + ((((size_t)b * 64 + t_e) * 4 + c) * 2 + branch) * REC_FLOATS;
    float* recB = part + ((((size_t)b * 64 + t_o) * 4 + c) * 2 + branch) * REC_FLOATS;

    if (s_lo >= smax) {  // empty chunk: zero both records
        unsigned int* pa_ = (unsigned int*)recA;
        unsigned int* pb_ = (unsigned int*)recB;
        for (int i = tid; i < REC_FLOATS; i += 256) { pa_[i] = 0u; pb_[i] = 0u; }
        return;
    }
    const bool emptyA = (s_lo > t_e);  // chunk == {t_o}
    if (emptyA) {
        unsigned int* pa_ = (unsigned int*)recA;
        for (int i = tid; i < REC_FLOATS; i += 256) pa_[i] = 0u;
    }

    const size_t bbase = (size_t)b * 4096;
    const unsigned short* kimg_b = kimg + (size_t)b * 524288;
    const unsigned short* vimg_b = vimg + (size_t)b * 524288;
    const int tid8 = tid * 8;
    const int l8 = l * 8;
    const f32x4 z4 = {0.f, 0.f, 0.f, 0.f};

    bf16x8 qfA[2], qfB[2];
    #pragma unroll
    for (int cc = 0; cc < 2; ++cc) {
        qfA[cc] = *(const bf16x8*)&q[(bbase + t_e * 64 + w * 16 + i16) * 128 + branch * 64 + cc * 32 + 8 * gq];
        qfB[cc] = *(const bf16x8*)&q[(bbase + t_o * 64 + w * 16 + i16) * 128 + branch * 64 + cc * 32 + 8 * gq];
    }

    float lsumA = 0.f, lsumB = 0.f;
    f32x4 acc[2][4][2];  // [qset][qg][j]  (dv slice w*32 + j*16)
    for (int qs = 0; qs < 2; ++qs)
        for (int qg = 0; qg < 4; ++qg)
            for (int j = 0; j < 2; ++j) acc[qs][qg][j] = z4;

    // P write slots (per cb, shared formula for both qsets; +qset*8 regions)
    int pdst[4];
    #pragma unroll
    for (int cb = 0; cb < 4; ++cb)
        pdst[cb] = ((w * 2 + (cb >> 1)) * 64 + ((cb & 1) * 2 + (gq >> 1)) * 16 + i16) * 8 + (gq & 1) * 4;

    uint4 kr0, kr1;
    bf16x8 vb00, vb01, vb10, vb11;  // V dv-slice frags, [j][cc]

#define K_ISSUE(s_) do {                                                            \
        const unsigned short* kp = &kimg_b[((size_t)(s_) * 2 + branch) * 4096];     \
        kr0 = *(const uint4*)&kp[tid8];                                             \
        kr1 = *(const uint4*)&kp[tid8 + 2048];                                      \
    } while (0)
#define V_ISSUE(s_) do {                                                            \
        const unsigned short* vp = &vimg_b[(size_t)(s_) * 8192 + w * 2048];         \
        vb00 = *(const bf16x8*)&vp[l8];                                             \
        vb01 = *(const bf16x8*)&vp[512 + l8];                                       \
        vb10 = *(const bf16x8*)&vp[1024 + l8];                                      \
        vb11 = *(const bf16x8*)&vp[1536 + l8];                                      \
    } while (0)

    K_ISSUE(s_lo);
    V_ISSUE(s_lo);
    #pragma unroll 1
    for (int s = s_lo; s < smax; ++s) {
        __syncthreads();                              // B1: prev PV done with ksf/psf
        *(uint4*)&ksf[tid8] = kr0;
        *(uint4*)&ksf[tid8 + 2048] = kr1;
        if (s + 1 < smax) K_ISSUE(s + 1);
        __syncthreads();                              // B2: ksf ready
        const bool aAct = (s != t_o);

        // ---- qset A (row t_e) ----
        if (aAct) {
            f32x4 sc[4];
            for (int cb = 0; cb < 4; ++cb) sc[cb] = z4;
            __builtin_amdgcn_s_setprio(1);
            #pragma unroll
            for (int cb = 0; cb < 4; ++cb)
                for (int cc = 0; cc < 2; ++cc) {
                    bf16x8 kf = *(const bf16x8*)&ksf[((cb * 2 + cc) * 64 + l) * 8];
                    sc[cb] = __builtin_amdgcn_mfma_f32_16x16x32_bf16(kf, qfA[cc], sc[cb], 0, 0, 0);
                }
            __builtin_amdgcn_s_setprio(0);
            if (s == t_e) {
                int ql = w * 16 + i16;
                for (int cb = 0; cb < 4; ++cb)
                    for (int r = 0; r < 4; ++r)
                        if (cb * 16 + gq * 4 + r > ql) sc[cb][r] = NEGINF;
            }
            #pragma unroll
            for (int cb = 0; cb < 4; ++cb) {
                float p0 = exp2f(fmaf(sc[cb][0], CEXP, -MOFF));
                float p1 = exp2f(fmaf(sc[cb][1], CEXP, -MOFF));
                float p2 = exp2f(fmaf(sc[cb][2], CEXP, -MOFF));
                float p3 = exp2f(fmaf(sc[cb][3], CEXP, -MOFF));
                lsumA += (p0 + p1) + (p2 + p3);
                uint2 pw;
                pw.x = cvt_pk_bf16(p0, p1);
                pw.y = cvt_pk_bf16(p2, p3);
                *(uint2*)&psf[pdst[cb]] = pw;
            }
        }
        // ---- qset B (row t_o) ----
        {
            f32x4 sc[4];
            for (int cb = 0; cb < 4; ++cb) sc[cb] = z4;
            __builtin_amdgcn_s_setprio(1);
            #pragma unroll
            for (int cb = 0; cb < 4; ++cb)
                for (int cc = 0; cc < 2; ++cc) {
                    bf16x8 kf = *(const bf16x8*)&ksf[((cb * 2 + cc) * 64 + l) * 8];
                    sc[cb] = __builtin_amdgcn_mfma_f32_16x16x32_bf16(kf, qfB[cc], sc[cb], 0, 0, 0);
                }
            __builtin_amdgcn_s_setprio(0);
            if (s == t_o) {
                int ql = w * 16 + i16;
                for (int cb = 0; cb < 4; ++cb)
                    for (int r = 0; r < 4; ++r)
                        if (cb * 16 + gq * 4 + r > ql) sc[cb][r] = NEGINF;
            }
            #pragma unroll
            for (int cb = 0; cb < 4; ++cb) {
                float p0 = exp2f(fmaf(sc[cb][0], CEXP, -MOFF));
                float p1 = exp2f(fmaf(sc[cb][1], CEXP, -MOFF));
                float p2 = exp2f(fmaf(sc[cb][2], CEXP, -MOFF));
                float p3 = exp2f(fmaf(sc[cb][3], CEXP, -MOFF));
                lsumB += (p0 + p1) + (p2 + p3);
                uint2 pw;
                pw.x = cvt_pk_bf16(p0, p1);
                pw.y = cvt_pk_bf16(p2, p3);
                *(uint2*)&psf[4096 + pdst[cb]] = pw;
            }
        }
        __syncthreads();                              // B3: psf complete (cross-wave)

        // ---- PV: all q x dv-slice [w*32, w*32+32), V in registers ----
        __builtin_amdgcn_s_setprio(1);
        if (aAct) {
            #pragma unroll
            for (int qg = 0; qg < 4; ++qg) {
                bf16x8 pa0 = *(const bf16x8*)&psf[(qg * 2 + 0) * 512 + l8];
                bf16x8 pa1 = *(const bf16x8*)&psf[(qg * 2 + 1) * 512 + l8];
                acc[0][qg][0] = __builtin_amdgcn_mfma_f32_16x16x32_bf16(pa0, vb00, acc[0][qg][0], 0, 0, 0);
                acc[0][qg][0] = __builtin_amdgcn_mfma_f32_16x16x32_bf16(pa1, vb01, acc[0][qg][0], 0, 0, 0);
                acc[0][qg][1] = __builtin_amdgcn_mfma_f32_16x16x32_bf16(pa0, vb10, acc[0][qg][1], 0, 0, 0);
                acc[0][qg][1] = __builtin_amdgcn_mfma_f32_16x16x32_bf16(pa1, vb11, acc[0][qg][1], 0, 0, 0);
            }
        }
        #pragma unroll
        for (int qg = 0; qg < 4; ++qg) {
            bf16x8 pa0 = *(const bf16x8*)&psf[4096 + (qg * 2 + 0) * 512 + l8];
            bf16x8 pa1 = *(const bf16x8*)&psf[4096 + (qg * 2 + 1) * 512 + l8];
            acc[1][qg][0] = __builtin_amdgcn_mfma_f32_16x16x32_bf16(pa0, vb00, acc[1][qg][0], 0, 0, 0);
            acc[1][qg][0] = __builtin_amdgcn_mfma_f32_16x16x32_bf16(pa1, vb01, acc[1][qg][0], 0, 0, 0);
            acc[1][qg][1] = __builtin_amdgcn_mfma_f32_16x16x32_bf16(pa0, vb10, acc[1][qg][1], 0, 0, 0);
            acc[1][qg][1] = __builtin_amdgcn_mfma_f32_16x16x32_bf16(pa1, vb11, acc[1][qg][1], 0, 0, 0);
        }
        __builtin_amdgcn_s_setprio(0);
        if (s + 1 < smax) V_ISSUE(s + 1);             // fly through next QK/softmax
    }
#undef K_ISSUE
#undef V_ISSUE

    // flush: lsum reduce across gq groups; O slices to both records
    lsumA += __shfl_xor(lsumA, 16);
    lsumA += __shfl_xor(lsumA, 32);
    lsumB += __shfl_xor(lsumB, 16);
    lsumB += __shfl_xor(lsumB, 32);
    if (!emptyA) {
        if (gq == 0) recA[w * 16 + i16] = lsumA;
        unsigned short* OA = (unsigned short*)(recA + 64);
        for (int qg = 0; qg < 4; ++qg)
            for (int j = 0; j < 2; ++j)
                for (int r = 0; r < 4; ++r)
                    OA[(qg * 16 + gq * 4 + r) * 128 + (w * 2 + j) * 16 + i16] = f2bf(acc[0][qg][j][r]);
    }
    {
        if (gq == 0) recB[w * 16 + i16] = lsumB;
        unsigned short* OB = (unsigned short*)(recB + 64);
        for (int qg = 0; qg < 4; ++qg)
            for (int j = 0; j < 2; ++j)
                for (int r = 0; r < 4; ++r)
                    OB[(qg * 16 + gq * 4 + r) * 128 + (w * 2 + j) * 16 + i16] = f2bf(acc[1][qg][j][r]);
    }
}

// ---------------- combine: sum 4 chunks per branch, normalize, o1 - lam*o2 ----------------
__global__ __launch_bounds__(256) void diff_combine(
    const float* __restrict__ part,
    const float* __restrict__ lq1, const float* __restrict__ lq2,
    const float* __restrict__ lk1, const float* __restrict__ lk2,
    float* __restrict__ out) {
    const int t = blockIdx.x, b = blockIdx.y;
    const int tid = threadIdx.x;
    __shared__ float sl[2][64];
    __shared__ float s_lam;

    const float* recbase = part + (((size_t)b * 64 + t) * 4) * 2 * REC_FLOATS;

    if (tid < 64) {
        float s1 = lq1[tid] * lk1[tid];
        float s2 = lq2[tid] * lk2[tid];
        for (int off = 32; off > 0; off >>= 1) {
            s1 += __shfl_xor(s1, off);
            s2 += __shfl_xor(s2, off);
        }
        if (tid == 0) s_lam = expf(s1) - expf(s2) + LAMBDA_INIT;
    }
    if (tid < 128) {
        int r = tid & 63, br = tid >> 6;
        float acc = 0.f;
        for (int c = 0; c < 4; ++c) acc += recbase[(c * 2 + br) * REC_FLOATS + r];
        sl[br][r] = acc;
    }
    __syncthreads();
    const float lam = s_lam;

    float* op = out + ((size_t)b * 4096 + (size_t)t * 64) * 128;
    for (int grp = 0; grp < 4; ++grp) {
        int gid = grp * 256 + tid;
        int e = gid * 8;
        int row = e >> 7;
        float o1[8] = {0, 0, 0, 0, 0, 0, 0, 0}, o2[8] = {0, 0, 0, 0, 0, 0, 0, 0};
        #pragma unroll
        for (int c = 0; c < 4; ++c) {
            const unsigned short* O0 = (const unsigned short*)(recbase + (c * 2 + 0) * REC_FLOATS + 64);
            const unsigned short* O1 = (const unsigned short*)(recbase + (c * 2 + 1) * REC_FLOATS + 64);
            uint4 u0 = *(const uint4*)&O0[e];
            uint4 u1 = *(const uint4*)&O1[e];
            const unsigned short* e0 = (const unsigned short*)&u0;
            const unsigned short* e1 = (const unsigned short*)&u1;
            #pragma unroll
            for (int j = 0; j < 8; ++j) {
                o1[j] += bf2f(e0[j]);
                o2[j] += bf2f(e1[j]);
            }
        }
        float l1inv = 1.0f / sl[0][row], l2inv = 1.0f / sl[1][row];
        float res[8];
        #pragma unroll
        for (int j = 0; j < 8; ++j) res[j] = o1[j] * l1inv - lam * o2[j] * l2inv;
        *(float4*)&op[e] = *(float4*)&res[0];
        *(float4*)&op[e + 4] = *(float4*)&res[4];
    }
}

extern "C" void kernel_launch(void* const* d_in, const int* in_sizes, int n_in,
                              void* d_out, int out_size, void* d_ws, size_t ws_size,
                              hipStream_t stream) {
    const float* x   = (const float*)d_in[0];
    const float* Wq  = (const float*)d_in[1];
    const float* Wk  = (const float*)d_in[2];
    const float* Wv  = (const float*)d_in[3];
    const float* lq1 = (const float*)d_in[4];
    const float* lq2 = (const float*)d_in[5];
    const float* lk1 = (const float*)d_in[6];
    const float* lk2 = (const float*)d_in[7];
    float* out = (float*)d_out;
    unsigned short* qkv = (unsigned short*)d_ws;
    float* part = (float*)((char*)d_ws + PART_OFF_BYTES);
    unsigned short* WT = (unsigned short*)((char*)d_ws + WT_OFF_BYTES);

    prep_wt<<<dim3(16, 2, 3), 256, 0, stream>>>(Wq, Wk, Wv, WT);
    qkv_gemm<<<dim3(128, 3), 256, 0, stream>>>(x, WT, qkv);

    const unsigned short* qb = qkv;
    const unsigned short* kb = qkv + K_OFF;
    const unsigned short* vtb = qkv + VT_OFF;
    diff_attn_pair<<<dim3(32, 4, 8), 256, 0, stream>>>(qb, kb, vtb, part);
    diff_combine<<<dim3(64, 4), 256, 0, stream>>>(part, lq1, lq2, lk1, lk2, out);
}

// Round 13
// 98.419 us; speedup vs baseline: 1.1450x; 1.1450x over previous
//
#include <hip/hip_runtime.h>
#include <hip/hip_bf16.h>

typedef __bf16 bf16x8 __attribute__((ext_vector_type(8)));
typedef float f32x4 __attribute__((ext_vector_type(4)));

#define LOG2E 1.4426950408889634f
#define LAMBDA_INIT 0.3555090675909693f
#define CEXP 0.18033688011112042f   // 0.125 * LOG2E
#define MOFF 11.541560327111708f    // 8 * LOG2E  (fixed raw max = 64)

// ws layout (bytes):
//  q    : [0, 4.19M)       bf16 [16384][128] row-major
//  kimg : [4.19M, 8.39M)   bf16 [4][64][2][8 regions][64 slots][8]  (frag image)
//  vimg : [8.39M, 12.58M)  bf16 [4][64][16 regions][64 slots][8]    (frag image)
//  part : [12.58M, 46.66M) 2048 recs x 16640B (l[64] f32 + O[64][128] bf16)
//  WT   : [46.66M, 47.45M) bf16 [3][128][1024]
#define K_OFF   ((size_t)16384 * 128)
#define VT_OFF  ((size_t)2 * 16384 * 128)
#define PART_OFF_BYTES ((size_t)12582912)
#define WT_OFF_BYTES   ((size_t)46661632)
#define REC_FLOATS 4160  // 64 l + 4096 words of bf16 O

__device__ __forceinline__ unsigned short f2bf(float f) {
    __hip_bfloat16 h = __float2bfloat16(f);
    unsigned short u;
    __builtin_memcpy(&u, &h, 2);
    return u;
}
__device__ __forceinline__ float bf2f(unsigned short u) {
    unsigned int x = ((unsigned int)u) << 16;
    float f;
    __builtin_memcpy(&f, &x, 4);
    return f;
}
__device__ __forceinline__ unsigned int cvt_pk_bf16(float a, float b) {
    unsigned int r;
    asm volatile("v_cvt_pk_bf16_f32 %0, %1, %2" : "=v"(r) : "v"(a), "v"(b));
    return r;
}

// ---------------- W pre-transpose: [1024][128] f32 -> [128][1024] bf16 ----------------
__global__ __launch_bounds__(256) void prep_wt(
    const float* __restrict__ Wq, const float* __restrict__ Wk,
    const float* __restrict__ Wv, unsigned short* __restrict__ WT) {
    const int kt = blockIdx.x, nt = blockIdx.y, mat = blockIdx.z;
    const float* W = (mat == 0) ? Wq : (mat == 1) ? Wk : Wv;
    unsigned short* O = WT + (size_t)mat * 128 * 1024;
    __shared__ float tb[64][65];
    const int r = threadIdx.x >> 2, c4 = (threadIdx.x & 3) * 16;
    for (int j = 0; j < 4; ++j) {
        float4 v = *(const float4*)&W[(size_t)(kt * 64 + r) * 128 + nt * 64 + c4 + j * 4];
        tb[r][c4 + j * 4 + 0] = v.x;
        tb[r][c4 + j * 4 + 1] = v.y;
        tb[r][c4 + j * 4 + 2] = v.z;
        tb[r][c4 + j * 4 + 3] = v.w;
    }
    __syncthreads();
    unsigned short tmp[16];
    for (int j = 0; j < 16; ++j) tmp[j] = f2bf(tb[c4 + j][r]);
    *(uint4*)&O[(size_t)(nt * 64 + r) * 1024 + kt * 64 + c4] = *(uint4*)&tmp[0];
    *(uint4*)&O[(size_t)(nt * 64 + r) * 1024 + kt * 64 + c4 + 8] = *(uint4*)&tmp[8];
}

// ---------------- QKV projection ----------------
// grid (128, 3): the 3 mats' row-r blocks map to the SAME XCD (128 % 8 == 0).
// K and V epilogues write the attention kernel's exact LDS/reg frag image.
__global__ __launch_bounds__(256) void qkv_gemm(
    const float* __restrict__ x, const unsigned short* __restrict__ WT,
    unsigned short* __restrict__ qkv) {
    const int tid = threadIdx.x;
    const int l = tid & 63, wid = tid >> 6;
    const int g = l >> 4, i16 = l & 15;
    const int row0 = blockIdx.x * 128;
    const int mat = blockIdx.y;
    const unsigned short* Wt = WT + (size_t)mat * 128 * 1024;

    __shared__ unsigned short smem[2][128][72];
    auto xs = smem[0];
    auto wt = smem[1];

    f32x4 acc[2][8];
    const f32x4 z4 = {0.f, 0.f, 0.f, 0.f};
    for (int a = 0; a < 2; ++a)
        for (int b = 0; b < 8; ++b) acc[a][b] = z4;

    for (int k0 = 0; k0 < 1024; k0 += 64) {
        __syncthreads();
        {   // stage x tile (128 x 64) f32 -> bf16
            const int c = (tid & 15) * 4;
            const int rbase = tid >> 4;
            #pragma unroll
            for (int it = 0; it < 8; ++it) {
                int r = rbase + it * 16;
                const float4 v = *(const float4*)&x[(size_t)(row0 + r) * 1024 + k0 + c];
                ushort4 pk = make_ushort4(f2bf(v.x), f2bf(v.y), f2bf(v.z), f2bf(v.w));
                *(ushort4*)&xs[r][c] = pk;
            }
        }
        {   // stage W^T tile (128 n x 64 k) bf16 vectorized
            #pragma unroll
            for (int it = 0; it < 4; ++it) {
                int lin = it * 256 + tid;
                int n = lin >> 3, k8 = (lin & 7) * 8;
                *(uint4*)&wt[n][k8] = *(const uint4*)&Wt[(size_t)n * 1024 + k0 + k8];
            }
        }
        __syncthreads();

        bf16x8 af[2][2];
        for (int rb = 0; rb < 2; ++rb)
            for (int c = 0; c < 2; ++c)
                af[rb][c] = *(const bf16x8*)&xs[wid * 32 + rb * 16 + i16][c * 32 + 8 * g];
        for (int nb = 0; nb < 8; ++nb) {
            bf16x8 b0 = *(const bf16x8*)&wt[nb * 16 + i16][8 * g];
            bf16x8 b1 = *(const bf16x8*)&wt[nb * 16 + i16][32 + 8 * g];
            for (int rb = 0; rb < 2; ++rb) {
                acc[rb][nb] = __builtin_amdgcn_mfma_f32_16x16x32_bf16(af[rb][0], b0, acc[rb][nb], 0, 0, 0);
                acc[rb][nb] = __builtin_amdgcn_mfma_f32_16x16x32_bf16(af[rb][1], b1, acc[rb][nb], 0, 0, 0);
            }
        }
    }

    __syncthreads();
    unsigned short(*ts)[136] = (unsigned short(*)[136]) & smem[0][0][0];
    for (int rb = 0; rb < 2; ++rb)
        for (int nb = 0; nb < 8; ++nb)
            for (int r = 0; r < 4; ++r)
                ts[wid * 32 + rb * 16 + g * 4 + r][nb * 16 + i16] = f2bf(acc[rb][nb][r]);
    __syncthreads();

    const int bq = row0 >> 12;            // batch
    const int s0b = (row0 & 4095) >> 6;   // first kv-tile of this row block
    if (mat == 0) {
        unsigned short* outp = qkv + (size_t)row0 * 128;
        #pragma unroll
        for (int it = 0; it < 8; ++it) {
            int tr = it * 16 + (tid >> 4), dv0 = (tid & 15) * 8;
            *(uint4*)&outp[tr * 128 + dv0] = *(const uint4*)&ts[tr][dv0];
        }
    } else if (mat == 1) {
        // K frag image: [(b*64+s)*2+branch][region=cb*2+cc][slot=gq*16+i16][8]
        unsigned short* kimg = qkv + K_OFF;
        #pragma unroll
        for (int it = 0; it < 8; ++it) {
            int lin = it * 256 + tid;      // 0..2047 slots of the 2-tile image
            int tile = lin >> 10;
            int branch_ = (lin >> 9) & 1;
            int region = (lin >> 6) & 7;
            int slot = lin & 63;
            int row = tile * 64 + (region >> 1) * 16 + (slot & 15);
            int d = branch_ * 64 + (region & 1) * 32 + (slot >> 4) * 8;
            uint4 vv = *(const uint4*)&ts[row][d];
            size_t off = ((size_t)((bq * 64 + s0b + tile) * 2 + branch_) * 4096) + (region * 64 + slot) * 8;
            *(uint4*)&kimg[off] = vv;
        }
    } else {
        // V frag image: [b*64+s][region=nb*2+cc][slot=gq*16+i16][8], elem = kv&7
        unsigned short* vimg = qkv + VT_OFF;
        #pragma unroll
        for (int it = 0; it < 8; ++it) {
            int lin = it * 256 + tid;      // 0..2047 slots of the 2-tile image
            int tile = lin >> 10;
            int rem = lin & 1023;
            int region = rem >> 6;         // 0..15
            int slot = rem & 63;
            int dv = (region >> 1) * 16 + (slot & 15);
            int kv0 = (region & 1) * 32 + (slot >> 4) * 8;
            unsigned short tmp[8];
            #pragma unroll
            for (int e = 0; e < 8; ++e) tmp[e] = ts[tile * 64 + kv0 + e][dv];
            size_t off = ((size_t)(bq * 64 + s0b + tile) * 8192) + (region * 64 + slot) * 8;
            *(uint4*)&vimg[off] = *(uint4*)tmp;
        }
    }
}

// ---------------- Differential causal flash attention, paired rows ----------------
// grid (32, 4, 8): z = c*2+branch. Block owns adjacent row PAIR
// (t_e = 62-2bxe, t_o = 63-2bxe) so every staged kv-tile serves two 64-row
// q-tiles. COMPLEMENT SWIZZLE: bxe = (c&1) ? 31-bx : bx. Same-CU blocks are
// ids {i, i+256, i+512, i+768} (256 = 8 XCD x 32 CU); +256 flips c parity ->
// complementary durations n(bx)+n(31-bx)=66 -> every CU gets 33 tile-units.
// Wave w: q-rows [w*16,w*16+16) of BOTH rows for QK/softmax; PV computes ALL
// q x dv-slice [32w,32w+32) with V in REGISTERS (direct frag-image loads).
// P via 16KB psf (cross-wave -> barrier before PV). LDS = 24KB.
__global__ __launch_bounds__(256, 3) void diff_attn_pair(
    const unsigned short* __restrict__ q, const unsigned short* __restrict__ kimg,
    const unsigned short* __restrict__ vimg,
    float* __restrict__ part) {
    const int bx = blockIdx.x, b = blockIdx.y;
    const int c = blockIdx.z >> 1, branch = blockIdx.z & 1;
    const int bxe = (c & 1) ? (31 - bx) : bx;   // complement swizzle (load balance)
    const int t_o = 63 - 2 * bxe, t_e = t_o - 1;
    const int n = t_o + 1;
    const int s_lo = (c * n) >> 2, smax = ((c + 1) * n) >> 2;

    const int tid = threadIdx.x;
    const int l = tid & 63, w = tid >> 6;
    const int gq = l >> 4, i16 = l & 15;
    const float NEGINF = -__builtin_inff();

    __shared__ unsigned short ksf[4096];  //  8 KB: [8 region][64 slot][8]
    __shared__ unsigned short psf[8192];  // 16 KB: [2 qset][4 qg][2 cc][64 slot][8]

    float* recA = part + ((((size_t)b * 64 + t_e) * 4 + c) * 2 + branch) * REC_FLOATS;
    float* recB = part + ((((size_t)b * 64 + t_o) * 4 + c) * 2 + branch) * REC_FLOATS;

    if (s_lo >= smax) {  // empty chunk: zero both records
        unsigned int* pa_ = (unsigned int*)recA;
        unsigned int* pb_ = (unsigned int*)recB;
        for (int i = tid; i < REC_FLOATS; i += 256) { pa_[i] = 0u; pb_[i] = 0u; }
        return;
    }
    const bool emptyA = (s_lo > t_e);  // chunk == {t_o}
    if (emptyA) {
        unsigned int* pa_ = (unsigned int*)recA;
        for (int i = tid; i < REC_FLOATS; i += 256) pa_[i] = 0u;
    }

    const size_t bbase = (size_t)b * 4096;
    const unsigned short* kimg_b = kimg + (size_t)b * 524288;
    const unsigned short* vimg_b = vimg + (size_t)b * 524288;
    const int tid8 = tid * 8;
    const int l8 = l * 8;
    const f32x4 z4 = {0.f, 0.f, 0.f, 0.f};

    bf16x8 qfA[2], qfB[2];
    #pragma unroll
    for (int cc = 0; cc < 2; ++cc) {
        qfA[cc] = *(const bf16x8*)&q[(bbase + t_e * 64 + w * 16 + i16) * 128 + branch * 64 + cc * 32 + 8 * gq];
        qfB[cc] = *(const bf16x8*)&q[(bbase + t_o * 64 + w * 16 + i16) * 128 + branch * 64 + cc * 32 + 8 * gq];
    }

    float lsumA = 0.f, lsumB = 0.f;
    f32x4 acc[2][4][2];  // [qset][qg][j]  (dv slice w*32 + j*16)
    for (int qs = 0; qs < 2; ++qs)
        for (int qg = 0; qg < 4; ++qg)
            for (int j = 0; j < 2; ++j) acc[qs][qg][j] = z4;

    // P write slots (per cb, shared formula for both qsets; +qset*8 regions)
    int pdst[4];
    #pragma unroll
    for (int cb = 0; cb < 4; ++cb)
        pdst[cb] = ((w * 2 + (cb >> 1)) * 64 + ((cb & 1) * 2 + (gq >> 1)) * 16 + i16) * 8 + (gq & 1) * 4;

    uint4 kr0, kr1;
    bf16x8 vb00, vb01, vb10, vb11;  // V dv-slice frags, [j][cc]

#define K_ISSUE(s_) do {                                                            \
        const unsigned short* kp = &kimg_b[((size_t)(s_) * 2 + branch) * 4096];     \
        kr0 = *(const uint4*)&kp[tid8];                                             \
        kr1 = *(const uint4*)&kp[tid8 + 2048];                                      \
    } while (0)
#define V_ISSUE(s_) do {                                                            \
        const unsigned short* vp = &vimg_b[(size_t)(s_) * 8192 + w * 2048];         \
        vb00 = *(const bf16x8*)&vp[l8];                                             \
        vb01 = *(const bf16x8*)&vp[512 + l8];                                       \
        vb10 = *(const bf16x8*)&vp[1024 + l8];                                      \
        vb11 = *(const bf16x8*)&vp[1536 + l8];                                      \
    } while (0)

    K_ISSUE(s_lo);
    V_ISSUE(s_lo);
    #pragma unroll 1
    for (int s = s_lo; s < smax; ++s) {
        __syncthreads();                              // B1: prev PV done with ksf/psf
        *(uint4*)&ksf[tid8] = kr0;
        *(uint4*)&ksf[tid8 + 2048] = kr1;
        if (s + 1 < smax) K_ISSUE(s + 1);
        __syncthreads();                              // B2: ksf ready
        const bool aAct = (s != t_o);

        // ---- qset A (row t_e) ----
        if (aAct) {
            f32x4 sc[4];
            for (int cb = 0; cb < 4; ++cb) sc[cb] = z4;
            __builtin_amdgcn_s_setprio(1);
            #pragma unroll
            for (int cb = 0; cb < 4; ++cb)
                for (int cc = 0; cc < 2; ++cc) {
                    bf16x8 kf = *(const bf16x8*)&ksf[((cb * 2 + cc) * 64 + l) * 8];
                    sc[cb] = __builtin_amdgcn_mfma_f32_16x16x32_bf16(kf, qfA[cc], sc[cb], 0, 0, 0);
                }
            __builtin_amdgcn_s_setprio(0);
            if (s == t_e) {
                int ql = w * 16 + i16;
                for (int cb = 0; cb < 4; ++cb)
                    for (int r = 0; r < 4; ++r)
                        if (cb * 16 + gq * 4 + r > ql) sc[cb][r] = NEGINF;
            }
            #pragma unroll
            for (int cb = 0; cb < 4; ++cb) {
                float p0 = exp2f(fmaf(sc[cb][0], CEXP, -MOFF));
                float p1 = exp2f(fmaf(sc[cb][1], CEXP, -MOFF));
                float p2 = exp2f(fmaf(sc[cb][2], CEXP, -MOFF));
                float p3 = exp2f(fmaf(sc[cb][3], CEXP, -MOFF));
                lsumA += (p0 + p1) + (p2 + p3);
                uint2 pw;
                pw.x = cvt_pk_bf16(p0, p1);
                pw.y = cvt_pk_bf16(p2, p3);
                *(uint2*)&psf[pdst[cb]] = pw;
            }
        }
        // ---- qset B (row t_o) ----
        {
            f32x4 sc[4];
            for (int cb = 0; cb < 4; ++cb) sc[cb] = z4;
            __builtin_amdgcn_s_setprio(1);
            #pragma unroll
            for (int cb = 0; cb < 4; ++cb)
                for (int cc = 0; cc < 2; ++cc) {
                    bf16x8 kf = *(const bf16x8*)&ksf[((cb * 2 + cc) * 64 + l) * 8];
                    sc[cb] = __builtin_amdgcn_mfma_f32_16x16x32_bf16(kf, qfB[cc], sc[cb], 0, 0, 0);
                }
            __builtin_amdgcn_s_setprio(0);
            if (s == t_o) {
                int ql = w * 16 + i16;
                for (int cb = 0; cb < 4; ++cb)
                    for (int r = 0; r < 4; ++r)
                        if (cb * 16 + gq * 4 + r > ql) sc[cb][r] = NEGINF;
            }
            #pragma unroll
            for (int cb = 0; cb < 4; ++cb) {
                float p0 = exp2f(fmaf(sc[cb][0], CEXP, -MOFF));
                float p1 = exp2f(fmaf(sc[cb][1], CEXP, -MOFF));
                float p2 = exp2f(fmaf(sc[cb][2], CEXP, -MOFF));
                float p3 = exp2f(fmaf(sc[cb][3], CEXP, -MOFF));
                lsumB += (p0 + p1) + (p2 + p3);
                uint2 pw;
                pw.x = cvt_pk_bf16(p0, p1);
                pw.y = cvt_pk_bf16(p2, p3);
                *(uint2*)&psf[4096 + pdst[cb]] = pw;
            }
        }
        __syncthreads();                              // B3: psf complete (cross-wave)

        // ---- PV: all q x dv-slice [w*32, w*32+32), V in registers ----
        __builtin_amdgcn_s_setprio(1);
        if (aAct) {
            #pragma unroll
            for (int qg = 0; qg < 4; ++qg) {
                bf16x8 pa0 = *(const bf16x8*)&psf[(qg * 2 + 0) * 512 + l8];
                bf16x8 pa1 = *(const bf16x8*)&psf[(qg * 2 + 1) * 512 + l8];
                acc[0][qg][0] = __builtin_amdgcn_mfma_f32_16x16x32_bf16(pa0, vb00, acc[0][qg][0], 0, 0, 0);
                acc[0][qg][0] = __builtin_amdgcn_mfma_f32_16x16x32_bf16(pa1, vb01, acc[0][qg][0], 0, 0, 0);
                acc[0][qg][1] = __builtin_amdgcn_mfma_f32_16x16x32_bf16(pa0, vb10, acc[0][qg][1], 0, 0, 0);
                acc[0][qg][1] = __builtin_amdgcn_mfma_f32_16x16x32_bf16(pa1, vb11, acc[0][qg][1], 0, 0, 0);
            }
        }
        #pragma unroll
        for (int qg = 0; qg < 4; ++qg) {
            bf16x8 pa0 = *(const bf16x8*)&psf[4096 + (qg * 2 + 0) * 512 + l8];
            bf16x8 pa1 = *(const bf16x8*)&psf[4096 + (qg * 2 + 1) * 512 + l8];
            acc[1][qg][0] = __builtin_amdgcn_mfma_f32_16x16x32_bf16(pa0, vb00, acc[1][qg][0], 0, 0, 0);
            acc[1][qg][0] = __builtin_amdgcn_mfma_f32_16x16x32_bf16(pa1, vb01, acc[1][qg][0], 0, 0, 0);
            acc[1][qg][1] = __builtin_amdgcn_mfma_f32_16x16x32_bf16(pa0, vb10, acc[1][qg][1], 0, 0, 0);
            acc[1][qg][1] = __builtin_amdgcn_mfma_f32_16x16x32_bf16(pa1, vb11, acc[1][qg][1], 0, 0, 0);
        }
        __builtin_amdgcn_s_setprio(0);
        if (s + 1 < smax) V_ISSUE(s + 1);             // fly through next QK/softmax
    }
#undef K_ISSUE
#undef V_ISSUE

    // flush: lsum reduce across gq groups; O slices to both records
    lsumA += __shfl_xor(lsumA, 16);
    lsumA += __shfl_xor(lsumA, 32);
    lsumB += __shfl_xor(lsumB, 16);
    lsumB += __shfl_xor(lsumB, 32);
    if (!emptyA) {
        if (gq == 0) recA[w * 16 + i16] = lsumA;
        unsigned short* OA = (unsigned short*)(recA + 64);
        for (int qg = 0; qg < 4; ++qg)
            for (int j = 0; j < 2; ++j)
                for (int r = 0; r < 4; ++r)
                    OA[(qg * 16 + gq * 4 + r) * 128 + (w * 2 + j) * 16 + i16] = f2bf(acc[0][qg][j][r]);
    }
    {
        if (gq == 0) recB[w * 16 + i16] = lsumB;
        unsigned short* OB = (unsigned short*)(recB + 64);
        for (int qg = 0; qg < 4; ++qg)
            for (int j = 0; j < 2; ++j)
                for (int r = 0; r < 4; ++r)
                    OB[(qg * 16 + gq * 4 + r) * 128 + (w * 2 + j) * 16 + i16] = f2bf(acc[1][qg][j][r]);
    }
}

// ---------------- combine: sum 4 chunks per branch, normalize, o1 - lam*o2 ----------------
__global__ __launch_bounds__(256) void diff_combine(
    const float* __restrict__ part,
    const float* __restrict__ lq1, const float* __restrict__ lq2,
    const float* __restrict__ lk1, const float* __restrict__ lk2,
    float* __restrict__ out) {
    const int t = blockIdx.x, b = blockIdx.y;
    const int tid = threadIdx.x;
    __shared__ float sl[2][64];
    __shared__ float s_lam;

    const float* recbase = part + (((size_t)b * 64 + t) * 4) * 2 * REC_FLOATS;

    if (tid < 64) {
        float s1 = lq1[tid] * lk1[tid];
        float s2 = lq2[tid] * lk2[tid];
        for (int off = 32; off > 0; off >>= 1) {
            s1 += __shfl_xor(s1, off);
            s2 += __shfl_xor(s2, off);
        }
        if (tid == 0) s_lam = expf(s1) - expf(s2) + LAMBDA_INIT;
    }
    if (tid < 128) {
        int r = tid & 63, br = tid >> 6;
        float acc = 0.f;
        for (int c = 0; c < 4; ++c) acc += recbase[(c * 2 + br) * REC_FLOATS + r];
        sl[br][r] = acc;
    }
    __syncthreads();
    const float lam = s_lam;

    float* op = out + ((size_t)b * 4096 + (size_t)t * 64) * 128;
    for (int grp = 0; grp < 4; ++grp) {
        int gid = grp * 256 + tid;
        int e = gid * 8;
        int row = e >> 7;
        float o1[8] = {0, 0, 0, 0, 0, 0, 0, 0}, o2[8] = {0, 0, 0, 0, 0, 0, 0, 0};
        #pragma unroll
        for (int c = 0; c < 4; ++c) {
            const unsigned short* O0 = (const unsigned short*)(recbase + (c * 2 + 0) * REC_FLOATS + 64);
            const unsigned short* O1 = (const unsigned short*)(recbase + (c * 2 + 1) * REC_FLOATS + 64);
            uint4 u0 = *(const uint4*)&O0[e];
            uint4 u1 = *(const uint4*)&O1[e];
            const unsigned short* e0 = (const unsigned short*)&u0;
            const unsigned short* e1 = (const unsigned short*)&u1;
            #pragma unroll
            for (int j = 0; j < 8; ++j) {
                o1[j] += bf2f(e0[j]);
                o2[j] += bf2f(e1[j]);
            }
        }
        float l1inv = 1.0f / sl[0][row], l2inv = 1.0f / sl[1][row];
        float res[8];
        #pragma unroll
        for (int j = 0; j < 8; ++j) res[j] = o1[j] * l1inv - lam * o2[j] * l2inv;
        *(float4*)&op[e] = *(float4*)&res[0];
        *(float4*)&op[e + 4] = *(float4*)&res[4];
    }
}

extern "C" void kernel_launch(void* const* d_in, const int* in_sizes, int n_in,
                              void* d_out, int out_size, void* d_ws, size_t ws_size,
                              hipStream_t stream) {
    const float* x   = (const float*)d_in[0];
    const float* Wq  = (const float*)d_in[1];
    const float* Wk  = (const float*)d_in[2];
    const float* Wv  = (const float*)d_in[3];
    const float* lq1 = (const float*)d_in[4];
    const float* lq2 = (const float*)d_in[5];
    const float* lk1 = (const float*)d_in[6];
    const float* lk2 = (const float*)d_in[7];
    float* out = (float*)d_out;
    unsigned short* qkv = (unsigned short*)d_ws;
    float* part = (float*)((char*)d_ws + PART_OFF_BYTES);
    unsigned short* WT = (unsigned short*)((char*)d_ws + WT_OFF_BYTES);

    prep_wt<<<dim3(16, 2, 3), 256, 0, stream>>>(Wq, Wk, Wv, WT);
    qkv_gemm<<<dim3(128, 3), 256, 0, stream>>>(x, WT, qkv);

    const unsigned short* qb = qkv;
    const unsigned short* kb = qkv + K_OFF;
    const unsigned short* vtb = qkv + VT_OFF;
    diff_attn_pair<<<dim3(32, 4, 8), 256, 0, stream>>>(qb, kb, vtb, part);
    diff_combine<<<dim3(64, 4), 256, 0, stream>>>(part, lq1, lq2, lk1, lk2, out);
}